// Round 3
// baseline (361.137 us; speedup 1.0000x reference)
//
#include <hip/hip_runtime.h>
#include <hip/hip_cooperative_groups.h>

namespace cg = cooperative_groups;

#define NGROUPS 16          // G
#define TPG     16          // threads (lanes) per group in the reduce = 16
#define CHUNK   32          // timesteps per chunk
#define EPS_F   1e-5f
#define VFLOOR  1e-6f

typedef float v4f __attribute__((ext_vector_type(4)));   // native vec for nontemporal store

__device__ __forceinline__ float sum8(const float4& a, const float4& b) {
    return ((a.x + a.y) + (a.z + a.w)) + ((b.x + b.y) + (b.z + b.w));
}

// Chan/Welford set-union merge: (na,ma,m2a) ∪= (nb,mb,m2b). Commutative.
__device__ __forceinline__ void wmerge(float& na, float& ma, float& m2a,
                                       float nb, float mb, float m2b) {
    if (nb > 0.f) {
        float nn = na + nb;
        float d  = mb - ma;
        float r  = nb / nn;
        ma  = fmaf(d, r, ma);
        m2a = m2a + m2b + d * d * (na * r);
        na  = nn;
    }
}

// ---------------- single fused cooperative kernel ----------------
// grid = B*NC = 512 blocks x 256 threads, cooperative launch (co-residency is
// VERIFIED by the runtime -> no spin deadlock possible; launch errors instead).
//
// phase 1: read x (only HBM read), group means -> s_gm (LDS), chunk Welford
//          aggregate; leaders publish {n,mean,m2} via agent-scope atomics.
// grid.sync()  -- replaces the K1->K2 kernel boundary (no full device drain of
//                 the write queue + no second launch + no gm_buf HBM round-trip)
// phase 2: lanes merge predecessor aggregates (L2 reads), shfl tree, prev merge.
// phase 3: leaders replay 32 sequential Welford steps from s_gm -> s_mean/s_rstd.
// phase 4: normalize (x re-read = L3 hit), nontemporal y store (y never re-read).
__global__ void __launch_bounds__(256, 2)
ts_coop(const float* __restrict__ x, const int* __restrict__ mask,
        float4* __restrict__ loc4,
        const int* __restrict__ prev_count, const float* __restrict__ prev_mean,
        const float* __restrict__ prev_var,
        const float* __restrict__ weight, const float* __restrict__ bias,
        float* __restrict__ y, float* __restrict__ out_count,
        float* __restrict__ out_mean, float* __restrict__ out_var,
        int B, int L, int D, int NC, float inv_gs)
{
    __shared__ float s_gm[NGROUPS][CHUNK];
    __shared__ float s_mean[NGROUPS][CHUNK + 1];   // +1 pad: leader writes stride 33
    __shared__ float s_rstd[NGROUPS][CHUNK + 1];

    const int b   = blockIdx.x / NC;
    const int c   = blockIdx.x % NC;
    const int tid = threadIdx.x;
    const int g   = tid / TPG;
    const int k   = tid & (TPG - 1);
    const bool leader = (k == 0);
    const int t0  = c * CHUNK;
    const int t1  = min(t0 + CHUNK, L);
    const int jmax = t1 - t0;
    const int chain = b * NGROUPS + g;

    // --- phase 1: group means + per-chunk Welford aggregate ---
    const float* xb = x + (size_t)b * L * D + tid * 8;
    const int*   mb = mask + (size_t)b * L;

    float n = 0.f, mean = 0.f, m2 = 0.f;
    #pragma unroll 4
    for (int t = t0; t < t1; ++t) {
        const float4* p = (const float4*)(xb + (size_t)t * D);
        float4 v0 = p[0], v1 = p[1];
        float s = sum8(v0, v1);
        s += __shfl_xor(s, 1, 64);
        s += __shfl_xor(s, 2, 64);
        s += __shfl_xor(s, 4, 64);
        s += __shfl_xor(s, 8, 64);
        float gmv = s * inv_gs;
        if (leader) s_gm[g][t - t0] = gmv;
        if (mb[t]) {                        // wave-uniform branch
            n += 1.f;
            float d = gmv - mean;
            mean += __fdividef(d, n);
            m2 = fmaf(d, gmv - mean, m2);
        }
    }

    // --- publish chunk aggregate (agent scope -> coherence point, cross-XCD safe) ---
    if (leader) {
        float* slot = (float*)&loc4[(size_t)(b * NC + c) * NGROUPS + g];
        __hip_atomic_store(slot + 0, n,    __ATOMIC_RELAXED, __HIP_MEMORY_SCOPE_AGENT);
        __hip_atomic_store(slot + 1, mean, __ATOMIC_RELAXED, __HIP_MEMORY_SCOPE_AGENT);
        __hip_atomic_store(slot + 2, m2,   __ATOMIC_RELAXED, __HIP_MEMORY_SCOPE_AGENT);
    }

    cg::this_grid().sync();   // deadlock-proof replacement for the spin/flags

    // --- phase 2: merge predecessor aggregates (exclusive prefix, L2 hits) ---
    float cn = 0.f, cm = 0.f, c2 = 0.f;
    for (int cp = k; cp < c; cp += TPG) {
        float* slot = (float*)&loc4[(size_t)(b * NC + cp) * NGROUPS + g];
        float vn = __hip_atomic_load(slot + 0, __ATOMIC_RELAXED, __HIP_MEMORY_SCOPE_AGENT);
        float vm = __hip_atomic_load(slot + 1, __ATOMIC_RELAXED, __HIP_MEMORY_SCOPE_AGENT);
        float v2 = __hip_atomic_load(slot + 2, __ATOMIC_RELAXED, __HIP_MEMORY_SCOPE_AGENT);
        wmerge(cn, cm, c2, vn, vm, v2);
    }
    // shfl tree over the 16 lanes of this group
    #pragma unroll
    for (int o = 1; o < TPG; o <<= 1) {
        float on = __shfl_xor(cn, o, 64);
        float om = __shfl_xor(cm, o, 64);
        float o2 = __shfl_xor(c2, o, 64);
        wmerge(cn, cm, c2, on, om, o2);
    }
    // merge prev-chain state (prev ∪ predecessor-union)
    float pn = (float)prev_count[b];
    float pm = prev_mean[chain];
    float p2 = prev_var[chain] * fmaxf(pn, 1.0f);
    wmerge(pn, pm, p2, cn, cm, c2);

    // --- phase 3: leaders replay per-timestep states into LDS ---
    if (leader) {
        const int* mrow = mb + t0;
        float rn = pn, rm = pm, r2 = p2;
        float var = fmaxf(__fdividef(r2, fmaxf(rn, 1.f)), VFLOOR);
        #pragma unroll 8
        for (int j = 0; j < jmax; ++j) {
            float gmv = s_gm[g][j];
            if (mrow[j]) {
                rn += 1.f;
                float d = gmv - rm;
                rm += __fdividef(d, rn);
                r2 = fmaf(d, gmv - rm, r2);
            }
            var = fmaxf(__fdividef(r2, fmaxf(rn, 1.f)), VFLOOR);
            s_mean[g][j] = rm;
            s_rstd[g][j] = rsqrtf(var + EPS_F);
        }
        if (c == NC - 1) {
            out_mean[chain] = rm;
            out_var[chain]  = var;
            if (g == 0) out_count[b] = rn;
        }
    }

    // --- phase 4: normalize the chunk ---
    const float4* wp = (const float4*)(weight + tid * 8);
    const float4* hp = (const float4*)(bias + tid * 8);
    float4 w0 = wp[0], w1 = wp[1];
    float4 h0 = hp[0], h1 = hp[1];
    w0.x += 1.f; w0.y += 1.f; w0.z += 1.f; w0.w += 1.f;
    w1.x += 1.f; w1.y += 1.f; w1.z += 1.f; w1.w += 1.f;

    __syncthreads();

    const float* xr = x + ((size_t)b * L + t0) * D + tid * 8;
    float*       yb = y + ((size_t)b * L + t0) * D + tid * 8;
    #pragma unroll 2
    for (int j = 0; j < jmax; ++j) {
        float m_ = s_mean[g][j];           // broadcast within 16-lane cohort
        float r_ = s_rstd[g][j];
        const float4* p = (const float4*)(xr + (size_t)j * D);
        float4 v0 = p[0], v1 = p[1];
        v4f o0, o1;
        o0.x = fmaf((v0.x - m_) * r_, w0.x, h0.x);
        o0.y = fmaf((v0.y - m_) * r_, w0.y, h0.y);
        o0.z = fmaf((v0.z - m_) * r_, w0.z, h0.z);
        o0.w = fmaf((v0.w - m_) * r_, w0.w, h0.w);
        o1.x = fmaf((v1.x - m_) * r_, w1.x, h1.x);
        o1.y = fmaf((v1.y - m_) * r_, w1.y, h1.y);
        o1.z = fmaf((v1.z - m_) * r_, w1.z, h1.z);
        o1.w = fmaf((v1.w - m_) * r_, w1.w, h1.w);
        v4f* q = (v4f*)(yb + (size_t)j * D);
        __builtin_nontemporal_store(o0, q);      // y never re-read: keep L3 for x
        __builtin_nontemporal_store(o1, q + 1);
    }
}

extern "C" void kernel_launch(void* const* d_in, const int* in_sizes, int n_in,
                              void* d_out, int out_size, void* d_ws, size_t ws_size,
                              hipStream_t stream) {
    const float* x          = (const float*)d_in[0];
    const int*   prev_count = (const int*)d_in[1];
    const float* prev_mean  = (const float*)d_in[2];
    const float* prev_var   = (const float*)d_in[3];
    const int*   mask       = (const int*)d_in[4];     // bool stored as int32
    const float* weight     = (const float*)d_in[5];
    const float* bias       = (const float*)d_in[6];

    const int B  = in_sizes[1];
    const int D  = in_sizes[5];
    const int L  = in_sizes[4] / B;
    const int NC = (L + CHUNK - 1) / CHUNK;
    const int BG = B * NGROUPS;
    const float inv_gs = (float)NGROUPS / (float)D;

    float* out = (float*)d_out;
    const size_t yN = (size_t)B * L * D;
    float* out_y     = out;
    float* out_count = out + yN;
    float* out_mean  = out + yN + B;
    float* out_var   = out + yN + B + BG;

    // workspace: loc4 [B*NC*G] float4 (128 KB)
    float4* loc4 = (float4*)d_ws;

    void* args[] = {
        (void*)&x, (void*)&mask, (void*)&loc4,
        (void*)&prev_count, (void*)&prev_mean, (void*)&prev_var,
        (void*)&weight, (void*)&bias,
        (void*)&out_y, (void*)&out_count, (void*)&out_mean, (void*)&out_var,
        (void*)&B, (void*)&L, (void*)&D, (void*)&NC, (void*)&inv_gs
    };

    (void)hipLaunchCooperativeKernel((const void*)ts_coop,
                                     dim3(B * NC), dim3(D / 8),
                                     args, 0, stream);
}

// Round 4
// 275.220 us; speedup vs baseline: 1.3122x; 1.3122x over previous
//
#include <hip/hip_runtime.h>

#define NGROUPS 16          // G
#define TPG     16          // threads (lanes) per group in the reduce = 16
#define CHUNK   8           // timesteps per chunk (8 -> 2048 blocks = full occupancy)
#define EPS_F   1e-5f
#define VFLOOR  1e-6f

typedef float v4f __attribute__((ext_vector_type(4)));   // native vec for nontemporal store

__device__ __forceinline__ float sum8(const float4& a, const float4& b) {
    return ((a.x + a.y) + (a.z + a.w)) + ((b.x + b.y) + (b.z + b.w));
}

// Chan/Welford set-union merge: (na,ma,m2a) ∪= (nb,mb,m2b). Commutative.
// Guard nb>0 keeps identity (0,0,0) and empty-chunk merges exact.
__device__ __forceinline__ void wmerge(float& na, float& ma, float& m2a,
                                       float nb, float mb, float m2b) {
    if (nb > 0.f) {
        float nn = na + nb;
        float d  = mb - ma;
        float r  = nb / nn;
        ma  = fmaf(d, r, ma);
        m2a = m2a + m2b + d * d * (na * r);
        na  = nn;
    }
}

// ---------------- K1: group means + per-chunk Welford aggregates ----------------
// grid = B*NC = 2048 blocks (8 blocks/CU -> 32 waves/CU: latency-hiding was the
// R3 bottleneck at 2 blocks/CU). block = D/8 = 256. The only HBM read of x.
// gm layout:   [b][c][g][j]          (contiguous per (chain,chunk) for K2 replay)
// loc4 layout: [b][g][c] float4{n,mean,m2,_}  (contiguous in c for K2 pred-reduce)
__global__ void __launch_bounds__(256)
ts_gm_agg(const float* __restrict__ x, const int* __restrict__ mask,
          float* __restrict__ gm_buf, float4* __restrict__ loc4,
          int B, int L, int D, int NC, float inv_gs)
{
    const int b   = blockIdx.x / NC;
    const int c   = blockIdx.x % NC;
    const int tid = threadIdx.x;
    const int g   = tid / TPG;
    const bool leader = (tid & (TPG - 1)) == 0;
    const int t0  = c * CHUNK;
    const int t1  = min(t0 + CHUNK, L);

    const float* xb = x + (size_t)b * L * D + tid * 8;
    const int*   mb = mask + (size_t)b * L;
    float* gmo = gm_buf + (((size_t)b * NC + c) * NGROUPS + g) * CHUNK;

    float n = 0.f, mean = 0.f, m2 = 0.f;
    #pragma unroll
    for (int t = t0; t < t1; ++t) {
        const float4* p = (const float4*)(xb + (size_t)t * D);
        float4 v0 = p[0], v1 = p[1];
        float s = sum8(v0, v1);
        s += __shfl_xor(s, 1, 64);
        s += __shfl_xor(s, 2, 64);
        s += __shfl_xor(s, 4, 64);
        s += __shfl_xor(s, 8, 64);
        float gmv = s * inv_gs;
        if (leader) gmo[t - t0] = gmv;
        if (mb[t]) {                       // wave-uniform branch
            n += 1.f;
            float d = gmv - mean;
            mean += __fdividef(d, n);
            m2 = fmaf(d, gmv - mean, m2);
        }
    }
    if (leader) {
        loc4[((size_t)b * NGROUPS + g) * NC + c] = make_float4(n, mean, m2, 0.f);
    }
}

// ---------------- K2: fused pred-reduce + replay + normalize ----------------
// grid = B*NC = 2048, block = 256. Block (b,c):
//  1. lanes (g,k) merge predecessor aggregates c'=k,k+16,... (L2 hits, <=32 iters)
//  2. 4-step shfl tree -> chunk-union per group; merge with prev-chain state
//  3. leaders replay 8 sequential Welford steps from gm -> s_mean/s_rstd (LDS)
//  4. all threads normalize the chunk (x re-read = L3 hit), nontemporal y store
__global__ void __launch_bounds__(256)
ts_fused(const float* __restrict__ x, const int* __restrict__ mask,
         const float* __restrict__ gm_buf, const float4* __restrict__ loc4,
         const int* __restrict__ prev_count, const float* __restrict__ prev_mean,
         const float* __restrict__ prev_var,
         const float* __restrict__ weight, const float* __restrict__ bias,
         float* __restrict__ y, float* __restrict__ out_count,
         float* __restrict__ out_mean, float* __restrict__ out_var,
         int B, int L, int D, int NC)
{
    __shared__ float s_mean[NGROUPS][CHUNK + 1];   // +1 pad: leader writes stride 9
    __shared__ float s_rstd[NGROUPS][CHUNK + 1];

    const int b   = blockIdx.x / NC;
    const int c   = blockIdx.x % NC;
    const int tid = threadIdx.x;
    const int g   = tid / TPG;
    const int k   = tid & (TPG - 1);
    const int chain = b * NGROUPS + g;

    // --- 1. parallel predecessor reduce (commutative set-union) ---
    float n = 0.f, mean = 0.f, m2 = 0.f;
    const float4* lrow = loc4 + (size_t)chain * NC;
    for (int cp = k; cp < c; cp += TPG) {
        float4 v = lrow[cp];
        wmerge(n, mean, m2, v.x, v.y, v.z);
    }
    // --- 2. shfl tree over the 16 lanes of this group ---
    #pragma unroll
    for (int o = 1; o < TPG; o <<= 1) {
        float on = __shfl_xor(n, o, 64);
        float om = __shfl_xor(mean, o, 64);
        float o2 = __shfl_xor(m2, o, 64);
        wmerge(n, mean, m2, on, om, o2);
    }
    // merge prev-chain state (prev ∪ chunk-union; commutative)
    {
        float pn = (float)prev_count[b];
        float pm = prev_mean[chain];
        float p2 = prev_var[chain] * fmaxf(pn, 1.0f);
        wmerge(pn, pm, p2, n, mean, m2);
        n = pn; mean = pm; m2 = p2;
    }

    // --- 3. leaders replay the chunk's per-timestep states into LDS ---
    const int t0 = c * CHUNK;
    const int jmax = min(CHUNK, L - t0);
    if (k == 0) {
        const float* gmo = gm_buf + (((size_t)b * NC + c) * NGROUPS + g) * CHUNK;
        const int*   mrow = mask + (size_t)b * L + t0;
        float var = fmaxf(__fdividef(m2, fmaxf(n, 1.f)), VFLOOR);
        #pragma unroll
        for (int j = 0; j < jmax; ++j) {
            float gmv = gmo[j];
            if (mrow[j]) {
                n += 1.f;
                float d = gmv - mean;
                mean += __fdividef(d, n);
                m2 = fmaf(d, gmv - mean, m2);
            }
            var = fmaxf(__fdividef(m2, fmaxf(n, 1.f)), VFLOOR);
            s_mean[g][j] = mean;
            s_rstd[g][j] = rsqrtf(var + EPS_F);
        }
        if (c == NC - 1) {
            out_mean[chain] = mean;
            out_var[chain]  = var;
            if (g == 0) out_count[b] = n;
        }
    }

    // --- 4. normalize the chunk ---
    const float4* wp = (const float4*)(weight + tid * 8);
    const float4* hp = (const float4*)(bias + tid * 8);
    float4 w0 = wp[0], w1 = wp[1];
    float4 h0 = hp[0], h1 = hp[1];
    w0.x += 1.f; w0.y += 1.f; w0.z += 1.f; w0.w += 1.f;
    w1.x += 1.f; w1.y += 1.f; w1.z += 1.f; w1.w += 1.f;

    __syncthreads();

    const float* xb = x + ((size_t)b * L + t0) * D + tid * 8;
    float*       yb = y + ((size_t)b * L + t0) * D + tid * 8;
    #pragma unroll 2
    for (int j = 0; j < jmax; ++j) {
        float m_ = s_mean[g][j];           // broadcast within 16-lane cohort
        float r_ = s_rstd[g][j];
        const float4* p = (const float4*)(xb + (size_t)j * D);
        float4 v0 = p[0], v1 = p[1];
        v4f o0, o1;
        o0.x = fmaf((v0.x - m_) * r_, w0.x, h0.x);
        o0.y = fmaf((v0.y - m_) * r_, w0.y, h0.y);
        o0.z = fmaf((v0.z - m_) * r_, w0.z, h0.z);
        o0.w = fmaf((v0.w - m_) * r_, w0.w, h0.w);
        o1.x = fmaf((v1.x - m_) * r_, w1.x, h1.x);
        o1.y = fmaf((v1.y - m_) * r_, w1.y, h1.y);
        o1.z = fmaf((v1.z - m_) * r_, w1.z, h1.z);
        o1.w = fmaf((v1.w - m_) * r_, w1.w, h1.w);
        v4f* q = (v4f*)(yb + (size_t)j * D);
        __builtin_nontemporal_store(o0, q);      // y never re-read: keep L3 for x
        __builtin_nontemporal_store(o1, q + 1);
    }
}

extern "C" void kernel_launch(void* const* d_in, const int* in_sizes, int n_in,
                              void* d_out, int out_size, void* d_ws, size_t ws_size,
                              hipStream_t stream) {
    const float* x          = (const float*)d_in[0];
    const int*   prev_count = (const int*)d_in[1];
    const float* prev_mean  = (const float*)d_in[2];
    const float* prev_var   = (const float*)d_in[3];
    const int*   mask       = (const int*)d_in[4];     // bool stored as int32
    const float* weight     = (const float*)d_in[5];
    const float* bias       = (const float*)d_in[6];

    const int B  = in_sizes[1];
    const int D  = in_sizes[5];
    const int L  = in_sizes[4] / B;
    const int NC = (L + CHUNK - 1) / CHUNK;     // 512
    const int BG = B * NGROUPS;
    const float inv_gs = (float)NGROUPS / (float)D;

    float* out = (float*)d_out;
    const size_t yN = (size_t)B * L * D;
    float* out_y     = out;
    float* out_count = out + yN;
    float* out_mean  = out + yN + B;
    float* out_var   = out + yN + B + BG;

    // workspace: gm_buf (B*NC*G*CHUNK floats = 1 MB), loc4 (B*G*NC float4 = 512 KB)
    float* ws = (float*)d_ws;
    const size_t gmN = (size_t)B * NC * NGROUPS * CHUNK;
    float*  gm_buf = ws;
    float4* loc4   = (float4*)(ws + gmN);

    dim3 blk(D / 8);   // 256

    ts_gm_agg<<<B * NC, blk, 0, stream>>>(x, mask, gm_buf, loc4, B, L, D, NC, inv_gs);

    ts_fused<<<B * NC, blk, 0, stream>>>(x, mask, gm_buf, loc4,
                                         prev_count, prev_mean, prev_var,
                                         weight, bias,
                                         out_y, out_count, out_mean, out_var,
                                         B, L, D, NC);
}